// Round 3
// baseline (64.976 us; speedup 1.0000x reference)
//
#include <hip/hip_runtime.h>

#define BATCH 262144
#define M 64

constexpr float KDT  = 1.0f / 48000.0f;
constexpr float EPSF = 1e-12f;

// DPP rotation-add within a 16-lane row: after ror 1,2,4,8 every lane of the
// 16-lane group holds the full group sum. Pure VALU (no LDS pipe, no lgkmcnt).
template <int CTRL>
__device__ __forceinline__ float dpp_ror_add(float x) {
    int xi = __builtin_bit_cast(int, x);
    int r  = __builtin_amdgcn_update_dpp(0, xi, CTRL, 0xF, 0xF, true);
    return x + __builtin_bit_cast(float, r);
}

__device__ __forceinline__ float rsum16(float x) {
    x = dpp_ror_add<0x121>(x);  // row_ror:1
    x = dpp_ror_add<0x122>(x);  // row_ror:2
    x = dpp_ror_add<0x124>(x);  // row_ror:4
    x = dpp_ror_add<0x128>(x);  // row_ror:8
    return x;
}

// 4 rows per wave (16 lanes each), 4 modes per thread: m = sl + 16*j.
__global__ __launch_bounds__(256) void sav_kernel(
    const float* __restrict__ y0,
    const float* __restrict__ dp,
    const float* __restrict__ dm,
    const float* __restrict__ omega_sq,
    const float* __restrict__ mu_p,
    const float* __restrict__ Phi_e,
    const float* __restrict__ fe_points,
    const int*   __restrict__ n_p,
    float* __restrict__ out)
{
    const int tid  = threadIdx.x;
    const int lane = tid & 63;
    const int sl   = lane & 15;        // sub-lane within row group
    const int sub  = lane >> 4;        // row within wave (0..3)
    const int wib  = tid >> 6;         // wave in block (0..3)
    const int b    = blockIdx.x * 16 + wib * 4 + sub;

    const int   n  = *n_p;
    const float mu = *mu_p;

    // per-mode constants (L1/L2-hot)
    float dpv[4], dmv[4], osq[4], phe[4];
    #pragma unroll
    for (int j = 0; j < 4; ++j) {
        const int m = sl + 16 * j;
        dpv[j] = dp[m];
        dmv[j] = dm[m];
        osq[j] = omega_sq[m];
        phe[j] = Phi_e[m];
    }

    const float* row = y0 + (size_t)b * (2 * M + 1);
    float q0v[4], p0v[4];
    #pragma unroll
    for (int j = 0; j < 4; ++j) {
        q0v[j] = row[sl + 16 * j];        // 64B contiguous per 16-lane group
        p0v[j] = row[M + sl + 16 * j];
    }
    const float psi0 = row[2 * M];        // broadcast within group
    const float fe   = fe_points[(size_t)b * 16 + n];

    // q_half, powers, local sum of qh^4
    float qh[4], q3[4];
    float lq4 = 0.0f;
    #pragma unroll
    for (int j = 0; j < 4; ++j) {
        const float q = q0v[j] + 0.5f * KDT * p0v[j];
        const float q2 = q * q;
        qh[j] = q;
        q3[j] = q2 * q;
        lq4 += q2 * q2;
    }

    // reduction A: s = sum(qh^4)
    const float s = rsum16(lq4);
    const float inv_psi = __builtin_amdgcn_rsqf(0.5f * s + EPSF);

    const float c = 0.5f * KDT * mu;
    float g0[4], a0[4], b0[4], idp[4];
    float ls1 = 0.0f, ls3 = 0.0f;
    #pragma unroll
    for (int j = 0; j < 4; ++j) {
        g0[j]  = -q3[j] * inv_psi;
        a0[j]  = c * g0[j];
        idp[j] = __builtin_amdgcn_rcpf(dpv[j]);
        b0[j]  = a0[j] * idp[j];
        ls1 += a0[j] * p0v[j];
        ls3 += a0[j] * b0[j];
    }

    // reductions B: s1 = sum(a0*p0), s3 = sum(a0*b0)
    const float s1 = rsum16(ls1);
    const float s3 = rsum16(ls3);

    // p1 pre-division (reference uses THIS value inside sum(b0*p1))
    const float mu2psi = mu * mu * psi0;
    float p1p[4];
    float ls2 = 0.0f;
    #pragma unroll
    for (int j = 0; j < 4; ++j) {
        p1p[j] = dmv[j] * p0v[j] - a0[j] * s1
               + KDT * (-osq[j] * qh[j] - mu2psi * g0[j] + phe[j] * fe);
        ls2 += b0[j] * p1p[j];
    }

    // reduction C: s2 = sum(b0 * p1_pre)
    const float s2 = rsum16(ls2);
    const float t  = s2 * __builtin_amdgcn_rcpf(1.0f + s3);

    float p1[4];
    float lsg = 0.0f;
    #pragma unroll
    for (int j = 0; j < 4; ++j) {
        p1[j] = p1p[j] * idp[j] - b0[j] * t;
        lsg += g0[j] * (0.5f * (p0v[j] + p1[j]));
    }

    // reduction D: sg = sum(g0 * p_half)
    const float sg   = rsum16(lsg);
    const float psi1 = psi0 + KDT * sg;

    float* orow = out + (size_t)b * (2 * M + 1);
    #pragma unroll
    for (int j = 0; j < 4; ++j) {
        orow[sl + 16 * j]     = qh[j] + 0.5f * KDT * p1[j];  // q1
        orow[M + sl + 16 * j] = p1[j];
    }
    if (sl == 0) orow[2 * M] = psi1;
}

extern "C" void kernel_launch(void* const* d_in, const int* in_sizes, int n_in,
                              void* d_out, int out_size, void* d_ws, size_t ws_size,
                              hipStream_t stream) {
    const float* y0        = (const float*)d_in[0];
    const float* dp        = (const float*)d_in[1];
    const float* dm        = (const float*)d_in[2];
    const float* omega_sq  = (const float*)d_in[3];
    const float* mu        = (const float*)d_in[4];
    const float* Phi_e     = (const float*)d_in[5];
    const float* fe_points = (const float*)d_in[6];
    const int*   n_p       = (const int*)d_in[7];
    float* out = (float*)d_out;

    const int blocks = BATCH / 16;  // 4 waves/block x 4 rows/wave
    sav_kernel<<<blocks, 256, 0, stream>>>(y0, dp, dm, omega_sq, mu, Phi_e,
                                           fe_points, n_p, out);
}

// Round 4
// 48.998 us; speedup vs baseline: 1.3261x; 1.3261x over previous
//
#include <hip/hip_runtime.h>

#define BATCH 262144
#define M 64
#define NROW 16              // rows per 256-thread block
#define ROWDW 129            // dwords per row in global layout
#define PADDW 132            // padded LDS row stride (multiple of 4 dwords = 16B)
#define NDW (NROW * ROWDW)   // 2064 dwords per block region
#define NV4 (NDW / 4)        // 516 float4 per block region

constexpr float KDT  = 1.0f / 48000.0f;
constexpr float EPSF = 1e-12f;

typedef float f4 __attribute__((ext_vector_type(4)));

// DPP rotation-add within a 16-lane row group: after ror 1,2,4,8 every lane
// holds the full 16-lane sum. Pure VALU, no LDS pipe.
template <int CTRL>
__device__ __forceinline__ float dpp_ror_add(float x) {
    int xi = __builtin_bit_cast(int, x);
    int r  = __builtin_amdgcn_update_dpp(0, xi, CTRL, 0xF, 0xF, true);
    return x + __builtin_bit_cast(float, r);
}
__device__ __forceinline__ float rsum16(float x) {
    x = dpp_ror_add<0x121>(x);  // row_ror:1
    x = dpp_ror_add<0x122>(x);  // row_ror:2
    x = dpp_ror_add<0x124>(x);  // row_ror:4
    x = dpp_ror_add<0x128>(x);  // row_ror:8
    return x;
}

__global__ __launch_bounds__(256) void sav_kernel(
    const float* __restrict__ y0,
    const float* __restrict__ dp,
    const float* __restrict__ dm,
    const float* __restrict__ omega_sq,
    const float* __restrict__ mu_p,
    const float* __restrict__ Phi_e,
    const float* __restrict__ fe_points,
    const int*   __restrict__ n_p,
    float* __restrict__ out)
{
    __shared__ float lds[NROW * PADDW];   // 8448 B

    const int tid = threadIdx.x;

    // ---------- load phase: fully coalesced, 16B-aligned float4 sweep ----------
    // block region byte offset = 8256 * blockIdx  (8256 % 16 == 0)
    const f4* gin = (const f4*)(y0 + (size_t)blockIdx.x * NDW);
    #pragma unroll
    for (int it = 0; it < 3; ++it) {
        const int i4 = tid + it * 256;
        if (i4 < NV4) {
            const f4 v = gin[i4];
            const unsigned d = (unsigned)i4 * 4u;
            #pragma unroll
            for (int e = 0; e < 4; ++e) {
                const unsigned dd  = d + e;
                const unsigned row = dd / 129u;           // magic-mul
                const unsigned col = dd - row * 129u;
                lds[row * PADDW + col] = v[e];
            }
        }
    }

    // independent loads issued before the barrier
    const int lane = tid & 63;
    const int sl   = lane & 15;                 // sub-lane within row group
    const int r    = ((tid >> 6) << 2) | (lane >> 4);   // local row 0..15
    const int b    = blockIdx.x * NROW + r;     // global row

    const int   n  = *n_p;
    const float mu = *mu_p;

    const f4 dpv = ((const f4*)dp)[sl];
    const f4 dmv = ((const f4*)dm)[sl];
    const f4 osq = ((const f4*)omega_sq)[sl];
    const f4 phe = ((const f4*)Phi_e)[sl];
    const float fe = fe_points[(size_t)b * 16 + n];

    __syncthreads();

    // ---------- compute phase: lane owns modes 4sl..4sl+3 ----------
    float* lrow = &lds[r * PADDW];
    const f4 q0v = *(const f4*)&lrow[4 * sl];          // byte r*528+16sl, 16B ok
    const f4 p0v = *(const f4*)&lrow[64 + 4 * sl];
    const float psi0 = lrow[128];

    f4 qh, q3;
    float lq4 = 0.0f;
    #pragma unroll
    for (int j = 0; j < 4; ++j) {
        const float q  = q0v[j] + 0.5f * KDT * p0v[j];
        const float q2 = q * q;
        qh[j] = q;
        q3[j] = q2 * q;
        lq4  += q2 * q2;
    }

    const float s = rsum16(lq4);                      // sum(qh^4)
    const float inv_psi = __builtin_amdgcn_rsqf(0.5f * s + EPSF);

    const float c = 0.5f * KDT * mu;
    f4 g0, a0, b0, idp;
    float ls1 = 0.0f, ls3 = 0.0f;
    #pragma unroll
    for (int j = 0; j < 4; ++j) {
        g0[j]  = -q3[j] * inv_psi;
        a0[j]  = c * g0[j];
        idp[j] = __builtin_amdgcn_rcpf(dpv[j]);
        b0[j]  = a0[j] * idp[j];
        ls1 += a0[j] * p0v[j];
        ls3 += a0[j] * b0[j];
    }

    const float s1 = rsum16(ls1);                     // sum(a0*p0)
    const float s3 = rsum16(ls3);                     // sum(a0*b0)

    // p1 pre-division (reference uses THIS value inside sum(b0*p1))
    const float mu2psi = mu * mu * psi0;
    f4 p1p;
    float ls2 = 0.0f;
    #pragma unroll
    for (int j = 0; j < 4; ++j) {
        p1p[j] = dmv[j] * p0v[j] - a0[j] * s1
               + KDT * (-osq[j] * qh[j] - mu2psi * g0[j] + phe[j] * fe);
        ls2 += b0[j] * p1p[j];
    }

    const float s2 = rsum16(ls2);                     // sum(b0*p1_pre)
    const float t  = s2 * __builtin_amdgcn_rcpf(1.0f + s3);

    f4 p1, q1;
    float lsg = 0.0f;
    #pragma unroll
    for (int j = 0; j < 4; ++j) {
        p1[j] = p1p[j] * idp[j] - b0[j] * t;
        lsg  += g0[j] * (0.5f * (p0v[j] + p1[j]));
        q1[j] = qh[j] + 0.5f * KDT * p1[j];
    }

    const float sg   = rsum16(lsg);                   // sum(g0*p_half)
    const float psi1 = psi0 + KDT * sg;

    // write results back to the same LDS cells (same-wave lockstep: all reads
    // above retired before these writes; other rows untouched)
    *(f4*)&lrow[4 * sl]      = q1;
    *(f4*)&lrow[64 + 4 * sl] = p1;
    if (sl == 0) lrow[128] = psi1;

    __syncthreads();

    // ---------- store phase: gather from LDS, nontemporal float4 sweep ----------
    f4* gout = (f4*)(out + (size_t)blockIdx.x * NDW);
    #pragma unroll
    for (int it = 0; it < 3; ++it) {
        const int i4 = tid + it * 256;
        if (i4 < NV4) {
            const unsigned d = (unsigned)i4 * 4u;
            f4 v;
            #pragma unroll
            for (int e = 0; e < 4; ++e) {
                const unsigned dd  = d + e;
                const unsigned row = dd / 129u;
                const unsigned col = dd - row * 129u;
                v[e] = lds[row * PADDW + col];
            }
            __builtin_nontemporal_store(v, &gout[i4]);
        }
    }
}

extern "C" void kernel_launch(void* const* d_in, const int* in_sizes, int n_in,
                              void* d_out, int out_size, void* d_ws, size_t ws_size,
                              hipStream_t stream) {
    const float* y0        = (const float*)d_in[0];
    const float* dp        = (const float*)d_in[1];
    const float* dm        = (const float*)d_in[2];
    const float* omega_sq  = (const float*)d_in[3];
    const float* mu        = (const float*)d_in[4];
    const float* Phi_e     = (const float*)d_in[5];
    const float* fe_points = (const float*)d_in[6];
    const int*   n_p       = (const int*)d_in[7];
    float* out = (float*)d_out;

    const int blocks = BATCH / NROW;   // 16384
    sav_kernel<<<blocks, 256, 0, stream>>>(y0, dp, dm, omega_sq, mu, Phi_e,
                                           fe_points, n_p, out);
}

// Round 5
// 46.297 us; speedup vs baseline: 1.4035x; 1.0584x over previous
//
#include <hip/hip_runtime.h>

#define BATCH 262144
#define M 64
#define NROW 32              // rows per block: 32*516B = 16512B = 129*128B -> every block region 128B-aligned
#define ROWDW 129            // dwords per row
#define NDW (NROW * ROWDW)   // 4128 dwords per block region
#define NV4 (NDW / 4)        // 1032 float4 = 2*512 + 8
#define NTHREADS 512

constexpr float KDT  = 1.0f / 48000.0f;
constexpr float EPSF = 1e-12f;

typedef float f4 __attribute__((ext_vector_type(4)));

// DPP rotation-add within a 16-lane row group: after ror 1,2,4,8 every lane
// holds the full 16-lane sum. Pure VALU, no LDS pipe.
template <int CTRL>
__device__ __forceinline__ float dpp_ror_add(float x) {
    int xi = __builtin_bit_cast(int, x);
    int r  = __builtin_amdgcn_update_dpp(0, xi, CTRL, 0xF, 0xF, true);
    return x + __builtin_bit_cast(float, r);
}
__device__ __forceinline__ float rsum16(float x) {
    x = dpp_ror_add<0x121>(x);  // row_ror:1
    x = dpp_ror_add<0x122>(x);  // row_ror:2
    x = dpp_ror_add<0x124>(x);  // row_ror:4
    x = dpp_ror_add<0x128>(x);  // row_ror:8
    return x;
}

__global__ __launch_bounds__(NTHREADS) void sav_kernel(
    const float* __restrict__ y0,
    const float* __restrict__ dp,
    const float* __restrict__ dm,
    const float* __restrict__ omega_sq,
    const float* __restrict__ mu_p,
    const float* __restrict__ Phi_e,
    const float* __restrict__ fe_points,
    const int*   __restrict__ n_p,
    float* __restrict__ out)
{
    // LDS mirrors the global layout exactly (stride 129 dwords, no padding).
    // 129 % 32 == 1 -> compute-phase scalar accesses are 2-way bank aliased (free).
    __shared__ float lds[NDW];   // 16512 B
    f4* lds4 = (f4*)lds;

    const int tid = threadIdx.x;

    // ---------- load phase: all global loads issued before any LDS write ----------
    const f4* gin = (const f4*)(y0 + (size_t)blockIdx.x * NDW);
    const f4 v0 = gin[tid];
    f4 v1, v2;
    v1 = gin[tid + NTHREADS];
    if (tid < NV4 - 2 * NTHREADS) v2 = gin[tid + 2 * NTHREADS];

    // per-row / per-lane setup (independent loads, overlap with the above)
    const int lane = tid & 63;
    const int sl   = lane & 15;                        // sub-lane within row group
    const int r    = ((tid >> 6) << 2) | (lane >> 4);  // local row 0..31
    const int b    = blockIdx.x * NROW + r;            // global row

    const int   n  = *n_p;
    const float mu = *mu_p;

    const f4 dpv = ((const f4*)dp)[sl];
    const f4 dmv = ((const f4*)dm)[sl];
    const f4 osq = ((const f4*)omega_sq)[sl];
    const f4 phe = ((const f4*)Phi_e)[sl];
    const float fe = fe_points[(size_t)b * 16 + n];

    lds4[tid] = v0;
    lds4[tid + NTHREADS] = v1;
    if (tid < NV4 - 2 * NTHREADS) lds4[tid + 2 * NTHREADS] = v2;

    __syncthreads();

    // ---------- compute phase: lane owns modes 4sl..4sl+3 of row r ----------
    float* lrow = &lds[r * ROWDW];
    float q0v[4], p0v[4];
    #pragma unroll
    for (int j = 0; j < 4; ++j) {
        q0v[j] = lrow[4 * sl + j];
        p0v[j] = lrow[M + 4 * sl + j];
    }
    const float psi0 = lrow[2 * M];

    float qh[4], q3[4];
    float lq4 = 0.0f;
    #pragma unroll
    for (int j = 0; j < 4; ++j) {
        const float q  = q0v[j] + 0.5f * KDT * p0v[j];
        const float q2 = q * q;
        qh[j] = q;
        q3[j] = q2 * q;
        lq4  += q2 * q2;
    }

    const float s = rsum16(lq4);                      // sum(qh^4)
    const float inv_psi = __builtin_amdgcn_rsqf(0.5f * s + EPSF);

    const float c = 0.5f * KDT * mu;
    float g0[4], a0[4], b0[4], idp[4];
    float ls1 = 0.0f, ls3 = 0.0f;
    #pragma unroll
    for (int j = 0; j < 4; ++j) {
        g0[j]  = -q3[j] * inv_psi;
        a0[j]  = c * g0[j];
        idp[j] = __builtin_amdgcn_rcpf(dpv[j]);
        b0[j]  = a0[j] * idp[j];
        ls1 += a0[j] * p0v[j];
        ls3 += a0[j] * b0[j];
    }

    const float s1 = rsum16(ls1);                     // sum(a0*p0)
    const float s3 = rsum16(ls3);                     // sum(a0*b0)

    // p1 pre-division (reference uses THIS value inside sum(b0*p1))
    const float mu2psi = mu * mu * psi0;
    float p1p[4];
    float ls2 = 0.0f;
    #pragma unroll
    for (int j = 0; j < 4; ++j) {
        p1p[j] = dmv[j] * p0v[j] - a0[j] * s1
               + KDT * (-osq[j] * qh[j] - mu2psi * g0[j] + phe[j] * fe);
        ls2 += b0[j] * p1p[j];
    }

    const float s2 = rsum16(ls2);                     // sum(b0*p1_pre)
    const float t  = s2 * __builtin_amdgcn_rcpf(1.0f + s3);

    float p1[4];
    float lsg = 0.0f;
    #pragma unroll
    for (int j = 0; j < 4; ++j) {
        p1[j] = p1p[j] * idp[j] - b0[j] * t;
        lsg  += g0[j] * (0.5f * (p0v[j] + p1[j]));
    }

    const float sg   = rsum16(lsg);                   // sum(g0*p_half)
    const float psi1 = psi0 + KDT * sg;

    // write results to the same LDS cells (same-wave lockstep; rows disjoint)
    #pragma unroll
    for (int j = 0; j < 4; ++j) {
        lrow[4 * sl + j]     = qh[j] + 0.5f * KDT * p1[j];  // q1
        lrow[M + 4 * sl + j] = p1[j];
    }
    if (sl == 0) lrow[2 * M] = psi1;

    __syncthreads();

    // ---------- store phase: contiguous, 128B-aligned, nontemporal ----------
    f4* gout = (f4*)(out + (size_t)blockIdx.x * NDW);
    __builtin_nontemporal_store(lds4[tid], &gout[tid]);
    __builtin_nontemporal_store(lds4[tid + NTHREADS], &gout[tid + NTHREADS]);
    if (tid < NV4 - 2 * NTHREADS)
        __builtin_nontemporal_store(lds4[tid + 2 * NTHREADS], &gout[tid + 2 * NTHREADS]);
}

extern "C" void kernel_launch(void* const* d_in, const int* in_sizes, int n_in,
                              void* d_out, int out_size, void* d_ws, size_t ws_size,
                              hipStream_t stream) {
    const float* y0        = (const float*)d_in[0];
    const float* dp        = (const float*)d_in[1];
    const float* dm        = (const float*)d_in[2];
    const float* omega_sq  = (const float*)d_in[3];
    const float* mu        = (const float*)d_in[4];
    const float* Phi_e     = (const float*)d_in[5];
    const float* fe_points = (const float*)d_in[6];
    const int*   n_p       = (const int*)d_in[7];
    float* out = (float*)d_out;

    const int blocks = BATCH / NROW;   // 8192
    sav_kernel<<<blocks, NTHREADS, 0, stream>>>(y0, dp, dm, omega_sq, mu, Phi_e,
                                                fe_points, n_p, out);
}

// Round 6
// 46.143 us; speedup vs baseline: 1.4081x; 1.0033x over previous
//
#include <hip/hip_runtime.h>

#define BATCH 262144
#define M 64
#define NROW 32              // 32*516B = 16512B = 129*128B -> block region 128B-aligned
#define ROWDW 129            // dwords per row
#define NDW (NROW * ROWDW)   // 4128 dwords per block region
#define NV4 (NDW / 4)        // 1032 float4 = 4*256 + 8
#define NT 256

constexpr float KDT  = 1.0f / 48000.0f;
constexpr float EPSF = 1e-12f;

typedef float f4 __attribute__((ext_vector_type(4)));

// DPP rotation-add within a 16-lane row group: after ror 1,2,4,8 every lane
// holds the full 16-lane sum. Pure VALU, no LDS pipe.
template <int CTRL>
__device__ __forceinline__ float dpp_ror_add(float x) {
    int xi = __builtin_bit_cast(int, x);
    int r  = __builtin_amdgcn_update_dpp(0, xi, CTRL, 0xF, 0xF, true);
    return x + __builtin_bit_cast(float, r);
}
__device__ __forceinline__ float rsum16(float x) {
    x = dpp_ror_add<0x121>(x);  // row_ror:1
    x = dpp_ror_add<0x122>(x);  // row_ror:2
    x = dpp_ror_add<0x124>(x);  // row_ror:4
    x = dpp_ror_add<0x128>(x);  // row_ror:8
    return x;
}

__global__ __launch_bounds__(NT) void sav_kernel(
    const float* __restrict__ y0,
    const float* __restrict__ dp,
    const float* __restrict__ dm,
    const float* __restrict__ omega_sq,
    const float* __restrict__ mu_p,
    const float* __restrict__ Phi_e,
    const float* __restrict__ fe_points,
    const int*   __restrict__ n_p,
    float* __restrict__ out)
{
    // LDS mirrors global layout (stride 129 dwords). 129 % 32 == 1 keeps
    // compute-phase scalar reads 2-way bank aliased (free per m136).
    __shared__ float lds[NDW];   // 16512 B -> 8 blocks/CU fits in 160KB
    f4* lds4 = (f4*)lds;

    const int tid = threadIdx.x;

    // ---------- load phase: issue all global loads first ----------
    const f4* gin = (const f4*)(y0 + (size_t)blockIdx.x * NDW);
    const f4 v0 = gin[tid];
    const f4 v1 = gin[tid + NT];
    const f4 v2 = gin[tid + 2 * NT];
    const f4 v3 = gin[tid + 3 * NT];
    f4 vt = {};
    if (tid < NV4 - 4 * NT) vt = gin[tid + 4 * NT];

    const int lane = tid & 63;
    const int sl   = lane & 15;       // sub-lane within 16-lane group
    const int g    = tid >> 4;        // group 0..15; handles rows g and g+16

    const int   n  = *n_p;
    const float mu = *mu_p;

    const f4 dpv = ((const f4*)dp)[sl];
    const f4 dmv = ((const f4*)dm)[sl];
    const f4 osq = ((const f4*)omega_sq)[sl];
    const f4 phe = ((const f4*)Phi_e)[sl];

    const int bA = blockIdx.x * NROW + g;   // row for pass 0
    const float feA = fe_points[(size_t)bA * 16 + n];
    const float feB = fe_points[(size_t)(bA + 16) * 16 + n];

    lds4[tid]          = v0;
    lds4[tid + NT]     = v1;
    lds4[tid + 2 * NT] = v2;
    lds4[tid + 3 * NT] = v3;
    if (tid < NV4 - 4 * NT) lds4[tid + 4 * NT] = vt;

    __syncthreads();

    // ---------- compute phase: 2 rows per group, sequential ----------
    const float c   = 0.5f * KDT * mu;
    const float mu2 = mu * mu;
    float idp[4];
    #pragma unroll
    for (int j = 0; j < 4; ++j) idp[j] = __builtin_amdgcn_rcpf(dpv[j]);

    #pragma unroll 1
    for (int rr = 0; rr < 2; ++rr) {
        const int r = g + 16 * rr;          // rows g, g+16: keeps banks 2-way
        const float fe = rr ? feB : feA;
        float* lrow = &lds[r * ROWDW];

        float q0v[4], p0v[4];
        #pragma unroll
        for (int j = 0; j < 4; ++j) {
            q0v[j] = lrow[4 * sl + j];
            p0v[j] = lrow[M + 4 * sl + j];
        }
        const float psi0 = lrow[2 * M];

        float qh[4], q3[4];
        float lq4 = 0.0f;
        #pragma unroll
        for (int j = 0; j < 4; ++j) {
            const float q  = q0v[j] + 0.5f * KDT * p0v[j];
            const float q2 = q * q;
            qh[j] = q;
            q3[j] = q2 * q;
            lq4  += q2 * q2;
        }

        const float s = rsum16(lq4);                      // sum(qh^4)
        const float inv_psi = __builtin_amdgcn_rsqf(0.5f * s + EPSF);

        float g0[4], b0[4];
        float ls1 = 0.0f, ls3 = 0.0f;
        #pragma unroll
        for (int j = 0; j < 4; ++j) {
            g0[j] = -q3[j] * inv_psi;
            const float a0 = c * g0[j];
            b0[j] = a0 * idp[j];
            ls1 += a0 * p0v[j];
            ls3 += a0 * b0[j];
        }

        const float s1 = rsum16(ls1);                     // sum(a0*p0)
        const float s3 = rsum16(ls3);                     // sum(a0*b0)

        // p1 pre-division (reference uses THIS value inside sum(b0*p1))
        const float mu2psi = mu2 * psi0;
        float p1p[4];
        float ls2 = 0.0f;
        #pragma unroll
        for (int j = 0; j < 4; ++j) {
            p1p[j] = dmv[j] * p0v[j] - (c * g0[j]) * s1
                   + KDT * (-osq[j] * qh[j] - mu2psi * g0[j] + phe[j] * fe);
            ls2 += b0[j] * p1p[j];
        }

        const float s2 = rsum16(ls2);                     // sum(b0*p1_pre)
        const float t  = s2 * __builtin_amdgcn_rcpf(1.0f + s3);

        float p1[4];
        float lsg = 0.0f;
        #pragma unroll
        for (int j = 0; j < 4; ++j) {
            p1[j] = p1p[j] * idp[j] - b0[j] * t;
            lsg  += g0[j] * (0.5f * (p0v[j] + p1[j]));
        }

        const float sg   = rsum16(lsg);                   // sum(g0*p_half)
        const float psi1 = psi0 + KDT * sg;

        // write back to the same LDS cells (rows disjoint across groups/passes)
        #pragma unroll
        for (int j = 0; j < 4; ++j) {
            lrow[4 * sl + j]     = qh[j] + 0.5f * KDT * p1[j];  // q1
            lrow[M + 4 * sl + j] = p1[j];
        }
        if (sl == 0) lrow[2 * M] = psi1;
    }

    __syncthreads();

    // ---------- store phase: contiguous, 128B-aligned, nontemporal ----------
    f4* gout = (f4*)(out + (size_t)blockIdx.x * NDW);
    __builtin_nontemporal_store(lds4[tid],          &gout[tid]);
    __builtin_nontemporal_store(lds4[tid + NT],     &gout[tid + NT]);
    __builtin_nontemporal_store(lds4[tid + 2 * NT], &gout[tid + 2 * NT]);
    __builtin_nontemporal_store(lds4[tid + 3 * NT], &gout[tid + 3 * NT]);
    if (tid < NV4 - 4 * NT)
        __builtin_nontemporal_store(lds4[tid + 4 * NT], &gout[tid + 4 * NT]);
}

extern "C" void kernel_launch(void* const* d_in, const int* in_sizes, int n_in,
                              void* d_out, int out_size, void* d_ws, size_t ws_size,
                              hipStream_t stream) {
    const float* y0        = (const float*)d_in[0];
    const float* dp        = (const float*)d_in[1];
    const float* dm        = (const float*)d_in[2];
    const float* omega_sq  = (const float*)d_in[3];
    const float* mu        = (const float*)d_in[4];
    const float* Phi_e     = (const float*)d_in[5];
    const float* fe_points = (const float*)d_in[6];
    const int*   n_p       = (const int*)d_in[7];
    float* out = (float*)d_out;

    const int blocks = BATCH / NROW;   // 8192
    sav_kernel<<<blocks, NT, 0, stream>>>(y0, dp, dm, omega_sq, mu, Phi_e,
                                          fe_points, n_p, out);
}